// Round 1
// baseline (306.836 us; speedup 1.0000x reference)
//
#include <hip/hip_runtime.h>

typedef float f32x4 __attribute__((ext_vector_type(4)));
typedef __bf16 bf16x8 __attribute__((ext_vector_type(8)));
typedef short short8v __attribute__((ext_vector_type(8)));
typedef unsigned short u16;

__device__ __forceinline__ u16 f2bf(float f) {
  unsigned int u = __float_as_uint(f);
  unsigned int r = (u + 0x7fffu + ((u >> 16) & 1u)) >> 16;
  return (u16)r;
}

__device__ __forceinline__ f32x4 mfma16(bf16x8 a, bf16x8 b, f32x4 c) {
  return __builtin_amdgcn_mfma_f32_16x16x32_bf16(a, b, c, 0, 0, 0);
}

__device__ __forceinline__ void gll16(const void* g, void* l) {
  __builtin_amdgcn_global_load_lds(
      (const __attribute__((address_space(1))) void*)g,
      (__attribute__((address_space(3))) void*)l, 16, 0, 0);
}

// ---------------- f32 -> bf16 convert ----------------
__global__ void cvt_kernel(const float* __restrict__ in, u16* __restrict__ out, int n8) {
  int idx = blockIdx.x * blockDim.x + threadIdx.x;
  int stride = gridDim.x * blockDim.x;
  for (int i = idx; i < n8; i += stride) {
    const float* p = in + (size_t)i * 8;
    f32x4 a = *(const f32x4*)p;
    f32x4 b = *(const f32x4*)(p + 4);
    short8v r;
#pragma unroll
    for (int j = 0; j < 4; ++j) {
      r[j] = (short)f2bf(a[j]);
      r[4 + j] = (short)f2bf(b[j]);
    }
    *(short8v*)(out + (size_t)i * 8) = r;
  }
}

// ---------------- bf16 GEMM: C = A @ B^T + bias ----------------
// A [M,K] row-major bf16, B [N,K] row-major bf16 (i.e. B^T), bias[N] f32.
// 128x128 tile, BK=32, 4 waves (2x2), each wave 64x64 = 4x4 MFMA tiles.
template <bool BF16OUT>
__global__ __launch_bounds__(256, 2) void gemm_bt(
    const u16* __restrict__ A, const u16* __restrict__ B,
    const float* __restrict__ bias, void* __restrict__ Cout,
    int M, int N, int K) {
  __shared__ u16 lA[128 * 32];
  __shared__ u16 lB[128 * 32];
  const int tid = threadIdx.x;
  const int wid = tid >> 6;
  const int lane = tid & 63;
  const int lr = lane & 15;
  const int lg = lane >> 4;
  const int bm = blockIdx.x * 128;
  const int bn = blockIdx.y * 128;
  const int wm = (wid >> 1) * 64;
  const int wn = (wid & 1) * 64;

  f32x4 acc[4][4] = {};

  for (int kt = 0; kt < K; kt += 32) {
    __syncthreads();  // protect LDS from overwrite while prev iter in flight
#pragma unroll
    for (int j = 0; j < 2; ++j) {
      int beta = tid * 16 + j * 4096;   // byte index within 8KB tile
      int row = beta >> 6;              // 64 B per row (32 bf16)
      int ce = (beta & 63) >> 1;        // col element
      gll16(A + (size_t)(bm + row) * K + kt + ce,
            (char*)lA + (wid << 10) + (j << 12));
      gll16(B + (size_t)(bn + row) * K + kt + ce,
            (char*)lB + (wid << 10) + (j << 12));
    }
    __syncthreads();  // drains vmcnt -> staged data visible
    bf16x8 af[4], bfr[4];
#pragma unroll
    for (int mt = 0; mt < 4; ++mt)
      af[mt] = *(const bf16x8*)&lA[(wm + mt * 16 + lr) * 32 + lg * 8];
#pragma unroll
    for (int nt = 0; nt < 4; ++nt)
      bfr[nt] = *(const bf16x8*)&lB[(wn + nt * 16 + lr) * 32 + lg * 8];
#pragma unroll
    for (int mt = 0; mt < 4; ++mt)
#pragma unroll
      for (int nt = 0; nt < 4; ++nt)
        acc[mt][nt] = mfma16(af[mt], bfr[nt], acc[mt][nt]);
  }

  // epilogue: C/D layout col=lane&15, row=(lane>>4)*4+reg
#pragma unroll
  for (int nt = 0; nt < 4; ++nt) {
    int col = bn + wn + nt * 16 + lr;
    float bv = bias[col];
#pragma unroll
    for (int mt = 0; mt < 4; ++mt) {
#pragma unroll
      for (int r = 0; r < 4; ++r) {
        int row = bm + wm + mt * 16 + lg * 4 + r;
        float val = acc[mt][nt][r] + bv;
        if (BF16OUT)
          ((u16*)Cout)[(size_t)row * N + col] = f2bf(val);
        else
          ((float*)Cout)[(size_t)row * N + col] = val;
      }
    }
  }
}

// ---------------- V transpose: qkv V-part -> Vt[bh][d][s] ----------------
__global__ void transpose_v(const u16* __restrict__ qkv, u16* __restrict__ vt) {
  __shared__ u16 t[64][72];  // pad to 72 (144 B rows, 16B-aligned)
  const int bh = blockIdx.x;
  const int b = bh >> 4, h = bh & 15;
  const int s0 = blockIdx.y * 64;
  const int tid = threadIdx.x;
  {
    int r = tid >> 2, c0 = (tid & 3) * 16;
    const u16* src = qkv + (size_t)(b * 2048 + s0 + r) * 3072 + 2048 + h * 64 + c0;
    *(short8v*)&t[r][c0] = *(const short8v*)src;
    *(short8v*)&t[r][c0 + 8] = *(const short8v*)(src + 8);
  }
  __syncthreads();
  {
    int d = tid >> 2, sc = (tid & 3) * 16;
    short8v o0, o1;
#pragma unroll
    for (int j = 0; j < 8; ++j) {
      o0[j] = (short)t[sc + j][d];
      o1[j] = (short)t[sc + 8 + j][d];
    }
    u16* dst = vt + ((size_t)bh * 64 + d) * 2048 + s0 + sc;
    *(short8v*)dst = o0;
    *(short8v*)(dst + 8) = o1;
  }
}

// ---------------- fused causal+ALiBi flash attention ----------------
// grid (S/64 qtiles, B*H). 4 waves, each owns 16 q rows. KV block = 64.
__global__ void attn_kernel(const u16* __restrict__ qkv, const u16* __restrict__ vt,
                            u16* __restrict__ aout) {
  __shared__ u16 p_lds[4][16][72];  // per-wave P tile, padded
  const int tid = threadIdx.x;
  const int wid = tid >> 6;
  const int lane = tid & 63;
  const int lr = lane & 15;
  const int lg = lane >> 4;
  const int qt = blockIdx.x;
  const int bh = blockIdx.y;
  const int b = bh >> 4, h = bh & 15;
  const int qbase = qt * 64;
  const int qr0 = qbase + wid * 16;

  const float LOG2E = 1.4426950408889634f;
  const float c1 = 0.125f * LOG2E;                       // scale * log2e
  const float c2 = exp2f(-(float)(h + 1) * 0.5f) * LOG2E;  // slope * log2e

  // Q fragments (A operand), kept in registers for the whole kv loop
  const u16* qrow = qkv + (size_t)(b * 2048 + qr0 + lr) * 3072 + h * 64;
  bf16x8 qf0 = *(const bf16x8*)(qrow + lg * 8);
  bf16x8 qf1 = *(const bf16x8*)(qrow + 32 + lg * 8);

  float m[4], l[4];
  f32x4 o[4];
#pragma unroll
  for (int r = 0; r < 4; ++r) { m[r] = -1e30f; l[r] = 0.f; }
#pragma unroll
  for (int dt = 0; dt < 4; ++dt) o[dt] = (f32x4){0.f, 0.f, 0.f, 0.f};

  float qidx[4];
#pragma unroll
  for (int r = 0; r < 4; ++r) qidx[r] = (float)(qr0 + lg * 4 + r);

  for (int kv = 0; kv <= qbase; kv += 64) {
    // ---- QK^T: scores s[nt] cover kv cols [kv+nt*16, kv+nt*16+16) ----
    f32x4 s[4];
    const u16* kbp = qkv + (size_t)(b * 2048 + kv) * 3072 + 1024 + h * 64;
#pragma unroll
    for (int nt = 0; nt < 4; ++nt) {
      const u16* kr = kbp + (size_t)(nt * 16 + lr) * 3072;
      bf16x8 k0 = *(const bf16x8*)(kr + lg * 8);
      bf16x8 k1 = *(const bf16x8*)(kr + 32 + lg * 8);
      f32x4 t = (f32x4){0.f, 0.f, 0.f, 0.f};
      t = mfma16(qf0, k0, t);
      t = mfma16(qf1, k1, t);
      s[nt] = t;
    }
    // ---- logits + online softmax (rows = lg*4+r, cols across 16 lanes) ----
    float rmax[4];
#pragma unroll
    for (int r = 0; r < 4; ++r) rmax[r] = -1e30f;
#pragma unroll
    for (int nt = 0; nt < 4; ++nt) {
      float kf = (float)(kv + nt * 16 + lr);
#pragma unroll
      for (int r = 0; r < 4; ++r) {
        float z = s[nt][r] * c1 + c2 * (kf - qidx[r]);
        z = (kf <= qidx[r]) ? z : -1e30f;
        s[nt][r] = z;
        rmax[r] = fmaxf(rmax[r], z);
      }
    }
#pragma unroll
    for (int r = 0; r < 4; ++r)
#pragma unroll
      for (int d = 1; d < 16; d <<= 1)
        rmax[r] = fmaxf(rmax[r], __shfl_xor(rmax[r], d));
    float fac[4], rsum[4];
#pragma unroll
    for (int r = 0; r < 4; ++r) {
      float mn = fmaxf(m[r], rmax[r]);
      fac[r] = exp2f(m[r] - mn);
      m[r] = mn;
      l[r] *= fac[r];
      rsum[r] = 0.f;
    }
#pragma unroll
    for (int nt = 0; nt < 4; ++nt)
#pragma unroll
      for (int r = 0; r < 4; ++r) {
        float e = exp2f(s[nt][r] - m[r]);
        s[nt][r] = e;
        rsum[r] += e;
      }
#pragma unroll
    for (int r = 0; r < 4; ++r) {
#pragma unroll
      for (int d = 1; d < 16; d <<= 1) rsum[r] += __shfl_xor(rsum[r], d);
      l[r] += rsum[r];
    }
#pragma unroll
    for (int dt = 0; dt < 4; ++dt)
#pragma unroll
      for (int r = 0; r < 4; ++r) o[dt][r] *= fac[r];

    // ---- P -> LDS (score layout) -> A-fragment layout ----
#pragma unroll
    for (int nt = 0; nt < 4; ++nt)
#pragma unroll
      for (int r = 0; r < 4; ++r)
        p_lds[wid][lg * 4 + r][nt * 16 + lr] = f2bf(s[nt][r]);
    // wave-private buffer: compiler inserts lgkmcnt ordering, no barrier needed
    bf16x8 pa0 = *(const bf16x8*)&p_lds[wid][lr][lg * 8];
    bf16x8 pa1 = *(const bf16x8*)&p_lds[wid][lr][32 + lg * 8];

    // ---- PV: o[dt] covers d cols [dt*16, dt*16+16) ----
    const u16* vbp = vt + (size_t)bh * 64 * 2048 + kv;
#pragma unroll
    for (int dt = 0; dt < 4; ++dt) {
      const u16* vr = vbp + (size_t)(dt * 16 + lr) * 2048;
      bf16x8 v0 = *(const bf16x8*)(vr + lg * 8);
      bf16x8 v1 = *(const bf16x8*)(vr + 32 + lg * 8);
      o[dt] = mfma16(pa0, v0, o[dt]);
      o[dt] = mfma16(pa1, v1, o[dt]);
    }
  }

  // ---- epilogue: out[b, q, h*64+d] bf16 ----
#pragma unroll
  for (int dt = 0; dt < 4; ++dt)
#pragma unroll
    for (int r = 0; r < 4; ++r) {
      float val = o[dt][r] / l[r];
      aout[(size_t)(b * 2048 + qr0 + lg * 4 + r) * 1024 + h * 64 + dt * 16 + lr] =
          f2bf(val);
    }
}

extern "C" void kernel_launch(void* const* d_in, const int* in_sizes, int n_in,
                              void* d_out, int out_size, void* d_ws, size_t ws_size,
                              hipStream_t stream) {
  (void)in_sizes; (void)n_in; (void)out_size; (void)ws_size;
  const float* x = (const float*)d_in[0];    // [2,2048,1024]
  const float* Wp = (const float*)d_in[1];   // [3072,1024]
  const float* bp = (const float*)d_in[2];   // [3072]
  const float* Wo = (const float*)d_in[3];   // [1024,1024]
  const float* bo = (const float*)d_in[4];   // [1024]
  float* out = (float*)d_out;

  char* ws = (char*)d_ws;
  u16* xb  = (u16*)(ws);                     // 8 MB, x bf16 [4096,1024]
  u16* wpb = (u16*)(ws + (size_t)(8u << 20));   // 6 MB
  u16* wob = (u16*)(ws + (size_t)(14u << 20));  // 2 MB
  u16* qkv = (u16*)(ws + (size_t)(16u << 20));  // 24 MB [4096,3072]
  u16* vt  = (u16*)(ws + (size_t)(40u << 20));  // 8 MB [32,64,2048]
  u16* ab  = xb;  // attention output reuses x_bf16 space (x dead after GEMM1)

  cvt_kernel<<<2048, 256, 0, stream>>>(x, xb, 4096 * 1024 / 8);
  cvt_kernel<<<1536, 256, 0, stream>>>(Wp, wpb, 3072 * 1024 / 8);
  cvt_kernel<<<512, 256, 0, stream>>>(Wo, wob, 1024 * 1024 / 8);
  gemm_bt<true><<<dim3(32, 24), 256, 0, stream>>>(xb, wpb, bp, qkv, 4096, 3072, 1024);
  transpose_v<<<dim3(32, 32), 256, 0, stream>>>(qkv, vt);
  attn_kernel<<<dim3(32, 32), 256, 0, stream>>>(qkv, vt, ab);
  gemm_bt<false><<<dim3(32, 8), 256, 0, stream>>>(ab, wob, bo, out, 4096, 1024, 1024);
}

// Round 2
// 304.652 us; speedup vs baseline: 1.0072x; 1.0072x over previous
//
#include <hip/hip_runtime.h>

typedef float f32x4 __attribute__((ext_vector_type(4)));
typedef __bf16 bf16x8 __attribute__((ext_vector_type(8)));
typedef unsigned short u16;

__device__ __forceinline__ f32x4 mfma16(bf16x8 a, bf16x8 b, f32x4 c) {
  return __builtin_amdgcn_mfma_f32_16x16x32_bf16(a, b, c, 0, 0, 0);
}

__device__ __forceinline__ void gll16(const void* g, void* l) {
  __builtin_amdgcn_global_load_lds(
      (const __attribute__((address_space(1))) void*)g,
      (__attribute__((address_space(3))) void*)l, 16, 0, 0);
}

// ---------------- f32 -> bf16 convert ----------------
__global__ void cvt_kernel(const float* __restrict__ in, __bf16* __restrict__ out, int n8) {
  int idx = blockIdx.x * blockDim.x + threadIdx.x;
  int stride = gridDim.x * blockDim.x;
  for (int i = idx; i < n8; i += stride) {
    const float* p = in + (size_t)i * 8;
    f32x4 a = *(const f32x4*)p;
    f32x4 b = *(const f32x4*)(p + 4);
    bf16x8 r;
#pragma unroll
    for (int j = 0; j < 4; ++j) {
      r[j] = (__bf16)a[j];
      r[4 + j] = (__bf16)b[j];
    }
    *(bf16x8*)(out + (size_t)i * 8) = r;
  }
}

// ---------------- bf16 GEMM: C = A @ B^T + bias ----------------
template <bool BF16OUT>
__global__ __launch_bounds__(256, 2) void gemm_bt(
    const u16* __restrict__ A, const u16* __restrict__ B,
    const float* __restrict__ bias, void* __restrict__ Cout,
    int M, int N, int K) {
  __shared__ u16 lA[128 * 32];
  __shared__ u16 lB[128 * 32];
  const int tid = threadIdx.x;
  const int wid = tid >> 6;
  const int lane = tid & 63;
  const int lr = lane & 15;
  const int lg = lane >> 4;
  const int bm = blockIdx.x * 128;
  const int bn = blockIdx.y * 128;
  const int wm = (wid >> 1) * 64;
  const int wn = (wid & 1) * 64;

  f32x4 acc[4][4] = {};

  for (int kt = 0; kt < K; kt += 32) {
    __syncthreads();
#pragma unroll
    for (int j = 0; j < 2; ++j) {
      int beta = tid * 16 + j * 4096;
      int row = beta >> 6;
      int ce = (beta & 63) >> 1;
      gll16(A + (size_t)(bm + row) * K + kt + ce,
            (char*)lA + (wid << 10) + (j << 12));
      gll16(B + (size_t)(bn + row) * K + kt + ce,
            (char*)lB + (wid << 10) + (j << 12));
    }
    __syncthreads();
    bf16x8 af[4], bfr[4];
#pragma unroll
    for (int mt = 0; mt < 4; ++mt)
      af[mt] = *(const bf16x8*)&lA[(wm + mt * 16 + lr) * 32 + lg * 8];
#pragma unroll
    for (int nt = 0; nt < 4; ++nt)
      bfr[nt] = *(const bf16x8*)&lB[(wn + nt * 16 + lr) * 32 + lg * 8];
#pragma unroll
    for (int mt = 0; mt < 4; ++mt)
#pragma unroll
      for (int nt = 0; nt < 4; ++nt)
        acc[mt][nt] = mfma16(af[mt], bfr[nt], acc[mt][nt]);
  }

#pragma unroll
  for (int nt = 0; nt < 4; ++nt) {
    int col = bn + wn + nt * 16 + lr;
    float bv = bias[col];
#pragma unroll
    for (int mt = 0; mt < 4; ++mt) {
#pragma unroll
      for (int r = 0; r < 4; ++r) {
        int row = bm + wm + mt * 16 + lg * 4 + r;
        float val = acc[mt][nt][r] + bv;
        if (BF16OUT)
          ((__bf16*)Cout)[(size_t)row * N + col] = (__bf16)val;
        else
          ((float*)Cout)[(size_t)row * N + col] = val;
      }
    }
  }
}

// ---------------- V transpose: qkv V-part -> Vt[bh][d][s] ----------------
typedef short short8v __attribute__((ext_vector_type(8)));
__global__ void transpose_v(const u16* __restrict__ qkv, u16* __restrict__ vt) {
  __shared__ u16 t[64][72];
  const int bh = blockIdx.x;
  const int b = bh >> 4, h = bh & 15;
  const int s0 = blockIdx.y * 64;
  const int tid = threadIdx.x;
  {
    int r = tid >> 2, c0 = (tid & 3) * 16;
    const u16* src = qkv + (size_t)(b * 2048 + s0 + r) * 3072 + 2048 + h * 64 + c0;
    *(short8v*)&t[r][c0] = *(const short8v*)src;
    *(short8v*)&t[r][c0 + 8] = *(const short8v*)(src + 8);
  }
  __syncthreads();
  {
    int d = tid >> 2, sc = (tid & 3) * 16;
    short8v o0, o1;
#pragma unroll
    for (int j = 0; j < 8; ++j) {
      o0[j] = (short)t[sc + j][d];
      o1[j] = (short)t[sc + 8 + j][d];
    }
    u16* dst = vt + ((size_t)bh * 64 + d) * 2048 + s0 + sc;
    *(short8v*)dst = o0;
    *(short8v*)(dst + 8) = o1;
  }
}

// ---------------- fused causal+ALiBi flash attention ----------------
// grid (32 qtiles desc, 32 bh). 4 waves/block, each wave 16 q rows. KV blk 64.
__global__ __launch_bounds__(256, 4) void attn_kernel(
    const u16* __restrict__ qkv, const u16* __restrict__ vt,
    __bf16* __restrict__ aout) {
  __shared__ __bf16 p_lds[4][16][72];
  const int tid = threadIdx.x;
  const int wid = tid >> 6;
  const int lane = tid & 63;
  const int lr = lane & 15;
  const int lg = lane >> 4;
  const int qt = 31 - blockIdx.x;     // descending: biggest blocks dispatch first
  const int bh = blockIdx.y;
  const int b = bh >> 4, h = bh & 15;
  const int qbase = qt * 64;
  const int qr0 = qbase + wid * 16;

  const float LOG2E = 1.4426950408889634f;
  const float c1 = 0.125f * LOG2E;                         // scale * log2e
  const float c2 = exp2f(-(float)(h + 1) * 0.5f) * LOG2E;  // slope * log2e

  const u16* qrow = qkv + (size_t)(b * 2048 + qr0 + lr) * 3072 + h * 64;
  bf16x8 qf0 = *(const bf16x8*)(qrow + lg * 8);
  bf16x8 qf1 = *(const bf16x8*)(qrow + 32 + lg * 8);

  bf16x8 ones;
#pragma unroll
  for (int j = 0; j < 8; ++j) ones[j] = (__bf16)1.0f;

  float m[4], l[4], cq[4];
  f32x4 o[4];
#pragma unroll
  for (int r = 0; r < 4; ++r) {
    m[r] = -1e30f;
    l[r] = 0.f;
    cq[r] = c2 * (float)(qr0 + lg * 4 + r);
  }
#pragma unroll
  for (int dt = 0; dt < 4; ++dt) o[dt] = (f32x4){0.f, 0.f, 0.f, 0.f};

  const u16* kbase = qkv + (size_t)(b * 2048) * 3072 + 1024 + h * 64;
  const u16* vbase = vt + (size_t)bh * 64 * 2048;

  bf16x8 ka[8];
#pragma unroll
  for (int nt = 0; nt < 4; ++nt) {
    const u16* kr = kbase + (size_t)(nt * 16 + lr) * 3072 + lg * 8;
    ka[2 * nt] = *(const bf16x8*)kr;
    ka[2 * nt + 1] = *(const bf16x8*)(kr + 32);
  }

  for (int kv = 0; kv <= qbase; kv += 64) {
    const bool diag = (kv == qbase);
    // ---- QK^T ----
    f32x4 s[4];
#pragma unroll
    for (int nt = 0; nt < 4; ++nt) {
      f32x4 t = (f32x4){0.f, 0.f, 0.f, 0.f};
      t = mfma16(qf0, ka[2 * nt], t);
      t = mfma16(qf1, ka[2 * nt + 1], t);
      s[nt] = t;
    }
    // ---- prefetch next K into the same registers (hidden under softmax+PV)
    if (kv + 64 <= qbase) {
      const u16* kbp = kbase + (size_t)(kv + 64) * 3072;
#pragma unroll
      for (int nt = 0; nt < 4; ++nt) {
        const u16* kr = kbp + (size_t)(nt * 16 + lr) * 3072 + lg * 8;
        ka[2 * nt] = *(const bf16x8*)kr;
        ka[2 * nt + 1] = *(const bf16x8*)(kr + 32);
      }
    }
    // ---- first half of V loads (k 0..31), in flight during softmax ----
    bf16x8 va0[4];
    const u16* vbp = vbase + kv;
#pragma unroll
    for (int dt = 0; dt < 4; ++dt)
      va0[dt] = *(const bf16x8*)(vbp + (size_t)(dt * 16 + lr) * 2048 + lg * 8);

    // ---- logits + online softmax ----
    float rmax[4];
#pragma unroll
    for (int nt = 0; nt < 4; ++nt) {
      float bnt = c2 * (float)(kv + nt * 16 + lr);
#pragma unroll
      for (int r = 0; r < 4; ++r)
        s[nt][r] = __builtin_fmaf(s[nt][r], c1, bnt - cq[r]);
    }
    if (diag) {
#pragma unroll
      for (int nt = 0; nt < 4; ++nt) {
        float kf = (float)(kv + nt * 16 + lr);
#pragma unroll
        for (int r = 0; r < 4; ++r) {
          float qi = (float)(qr0 + lg * 4 + r);
          if (kf > qi) s[nt][r] = -1e30f;
        }
      }
    }
#pragma unroll
    for (int r = 0; r < 4; ++r)
      rmax[r] = fmaxf(fmaxf(s[0][r], s[1][r]), fmaxf(s[2][r], s[3][r]));
#pragma unroll
    for (int r = 0; r < 4; ++r)
#pragma unroll
      for (int d = 1; d < 16; d <<= 1)
        rmax[r] = fmaxf(rmax[r], __shfl_xor(rmax[r], d));
    float fac[4];
#pragma unroll
    for (int r = 0; r < 4; ++r) {
      float mn = fmaxf(m[r], rmax[r]);
      fac[r] = __builtin_amdgcn_exp2f(m[r] - mn);
      m[r] = mn;
      l[r] *= fac[r];
    }
#pragma unroll
    for (int dt = 0; dt < 4; ++dt)
#pragma unroll
      for (int r = 0; r < 4; ++r) o[dt][r] *= fac[r];
#pragma unroll
    for (int nt = 0; nt < 4; ++nt)
#pragma unroll
      for (int r = 0; r < 4; ++r) {
        float e = __builtin_amdgcn_exp2f(s[nt][r] - m[r]);
        p_lds[wid][lg * 4 + r][nt * 16 + lr] = (__bf16)e;
      }

    // ---- second half of V loads (k 32..63) ----
    bf16x8 va1[4];
#pragma unroll
    for (int dt = 0; dt < 4; ++dt)
      va1[dt] = *(const bf16x8*)(vbp + (size_t)(dt * 16 + lr) * 2048 + 32 + lg * 8);

    // wave-private LDS buffer: compiler orders via lgkmcnt, no barrier needed
    bf16x8 pa0 = *(const bf16x8*)&p_lds[wid][lr][lg * 8];
    bf16x8 pa1 = *(const bf16x8*)&p_lds[wid][lr][32 + lg * 8];

    // ---- row-sum via ones-MFMA: t[r] = sum_k P[row,k] ----
    {
      f32x4 t = (f32x4){0.f, 0.f, 0.f, 0.f};
      t = mfma16(pa0, ones, t);
      t = mfma16(pa1, ones, t);
#pragma unroll
      for (int r = 0; r < 4; ++r) l[r] += t[r];
    }

    // ---- PV ----
#pragma unroll
    for (int dt = 0; dt < 4; ++dt) o[dt] = mfma16(pa0, va0[dt], o[dt]);
#pragma unroll
    for (int dt = 0; dt < 4; ++dt) o[dt] = mfma16(pa1, va1[dt], o[dt]);
  }

  // ---- epilogue ----
#pragma unroll
  for (int dt = 0; dt < 4; ++dt)
#pragma unroll
    for (int r = 0; r < 4; ++r) {
      float val = o[dt][r] / l[r];
      aout[(size_t)(b * 2048 + qr0 + lg * 4 + r) * 1024 + h * 64 + dt * 16 + lr] =
          (__bf16)val;
    }
}

extern "C" void kernel_launch(void* const* d_in, const int* in_sizes, int n_in,
                              void* d_out, int out_size, void* d_ws, size_t ws_size,
                              hipStream_t stream) {
  (void)in_sizes; (void)n_in; (void)out_size; (void)ws_size;
  const float* x = (const float*)d_in[0];
  const float* Wp = (const float*)d_in[1];
  const float* bp = (const float*)d_in[2];
  const float* Wo = (const float*)d_in[3];
  const float* bo = (const float*)d_in[4];
  float* out = (float*)d_out;

  char* ws = (char*)d_ws;
  u16* xb  = (u16*)(ws);
  u16* wpb = (u16*)(ws + (size_t)(8u << 20));
  u16* wob = (u16*)(ws + (size_t)(14u << 20));
  u16* qkv = (u16*)(ws + (size_t)(16u << 20));
  u16* vt  = (u16*)(ws + (size_t)(40u << 20));
  u16* ab  = xb;

  cvt_kernel<<<2048, 256, 0, stream>>>(x, (__bf16*)xb, 4096 * 1024 / 8);
  cvt_kernel<<<1536, 256, 0, stream>>>(Wp, (__bf16*)wpb, 3072 * 1024 / 8);
  cvt_kernel<<<512, 256, 0, stream>>>(Wo, (__bf16*)wob, 1024 * 1024 / 8);
  gemm_bt<true><<<dim3(32, 24), 256, 0, stream>>>(xb, wpb, bp, qkv, 4096, 3072, 1024);
  transpose_v<<<dim3(32, 32), 256, 0, stream>>>(qkv, vt);
  attn_kernel<<<dim3(32, 32), 256, 0, stream>>>(qkv, vt, (__bf16*)ab);
  gemm_bt<false><<<dim3(32, 8), 256, 0, stream>>>(ab, wob, bo, out, 4096, 1024, 1024);
}

// Round 3
// 171.657 us; speedup vs baseline: 1.7875x; 1.7748x over previous
//
#include <hip/hip_runtime.h>

typedef float f32x4 __attribute__((ext_vector_type(4)));
typedef __bf16 bf16x8 __attribute__((ext_vector_type(8)));
typedef unsigned short u16;

__device__ __forceinline__ f32x4 mfma16(bf16x8 a, bf16x8 b, f32x4 c) {
  return __builtin_amdgcn_mfma_f32_16x16x32_bf16(a, b, c, 0, 0, 0);
}

__device__ __forceinline__ void gll16(const void* g, void* l) {
  __builtin_amdgcn_global_load_lds(
      (const __attribute__((address_space(1))) void*)g,
      (__attribute__((address_space(3))) void*)l, 16, 0, 0);
}

// ---------------- f32 -> bf16 convert ----------------
__global__ void cvt_kernel(const float* __restrict__ in, __bf16* __restrict__ out, int n8) {
  int idx = blockIdx.x * blockDim.x + threadIdx.x;
  int stride = gridDim.x * blockDim.x;
  for (int i = idx; i < n8; i += stride) {
    const float* p = in + (size_t)i * 8;
    f32x4 a = *(const f32x4*)p;
    f32x4 b = *(const f32x4*)(p + 4);
    bf16x8 r;
#pragma unroll
    for (int j = 0; j < 4; ++j) {
      r[j] = (__bf16)a[j];
      r[4 + j] = (__bf16)b[j];
    }
    *(bf16x8*)(out + (size_t)i * 8) = r;
  }
}

// ---------------- bf16 GEMM: C = A @ B^T + bias ----------------
// MODE 0: plain f32 output to Cout.
// MODE 1: QKV pack: Q -> qb [4096,1024]; K -> kp tiles [bh][t][s'][d] swizzled;
//         V -> vp tiles [bh][t][d][s'] swizzled. chunk(col16B) ^= (row&7).
template <int MODE>
__global__ __launch_bounds__(256, 2) void gemm_bt(
    const u16* __restrict__ A, const u16* __restrict__ B,
    const float* __restrict__ bias, float* __restrict__ Cout,
    __bf16* __restrict__ qb, __bf16* __restrict__ kp, __bf16* __restrict__ vp,
    int M, int N, int K) {
  __shared__ u16 lA[128 * 32];
  __shared__ u16 lB[128 * 32];
  const int tid = threadIdx.x;
  const int wid = tid >> 6;
  const int lane = tid & 63;
  const int lr = lane & 15;
  const int lg = lane >> 4;
  const int bm = blockIdx.x * 128;
  const int bn = blockIdx.y * 128;
  const int wm = (wid >> 1) * 64;
  const int wn = (wid & 1) * 64;

  f32x4 acc[4][4] = {};

  for (int kt = 0; kt < K; kt += 32) {
    __syncthreads();
#pragma unroll
    for (int j = 0; j < 2; ++j) {
      int beta = tid * 16 + j * 4096;
      int row = beta >> 6;
      int ce = (beta & 63) >> 1;
      gll16(A + (size_t)(bm + row) * K + kt + ce,
            (char*)lA + (wid << 10) + (j << 12));
      gll16(B + (size_t)(bn + row) * K + kt + ce,
            (char*)lB + (wid << 10) + (j << 12));
    }
    __syncthreads();
    bf16x8 af[4], bfr[4];
#pragma unroll
    for (int mt = 0; mt < 4; ++mt)
      af[mt] = *(const bf16x8*)&lA[(wm + mt * 16 + lr) * 32 + lg * 8];
#pragma unroll
    for (int nt = 0; nt < 4; ++nt)
      bfr[nt] = *(const bf16x8*)&lB[(wn + nt * 16 + lr) * 32 + lg * 8];
#pragma unroll
    for (int mt = 0; mt < 4; ++mt)
#pragma unroll
      for (int nt = 0; nt < 4; ++nt)
        acc[mt][nt] = mfma16(af[mt], bfr[nt], acc[mt][nt]);
  }

#pragma unroll
  for (int nt = 0; nt < 4; ++nt) {
    int col = bn + wn + nt * 16 + lr;
    float bv = bias[col];
#pragma unroll
    for (int mt = 0; mt < 4; ++mt) {
#pragma unroll
      for (int r = 0; r < 4; ++r) {
        int row = bm + wm + mt * 16 + lg * 4 + r;
        float val = acc[mt][nt][r] + bv;
        if (MODE == 0) {
          Cout[(size_t)row * N + col] = val;
        } else {
          __bf16 bx = (__bf16)val;
          int b = row >> 11, s = row & 2047;
          int third = col >> 10, hd = col & 1023;
          int h = hd >> 6, d = hd & 63;
          if (third == 0) {
            qb[(size_t)row * 1024 + hd] = bx;
          } else {
            int bh = b * 16 + h, t = s >> 6, sr = s & 63;
            size_t tb = ((size_t)(bh * 32 + t)) * 4096;
            if (third == 1)
              kp[tb + sr * 64 + (((d >> 3) ^ (sr & 7)) << 3) + (d & 7)] = bx;
            else
              vp[tb + d * 64 + ((((sr >> 3)) ^ (d & 7)) << 3) + (sr & 7)] = bx;
          }
        }
      }
    }
  }
}

// ---------------- fused causal+ALiBi flash attention ----------------
// grid (32 qtiles desc, 32 bh). 4 waves/block, each wave 16 q rows. KV blk 64.
// K/V staged cooperatively into double-buffered LDS from packed swizzled tiles.
__global__ __launch_bounds__(256, 3) void attn_kernel(
    const __bf16* __restrict__ qb, const __bf16* __restrict__ kp,
    const __bf16* __restrict__ vp, __bf16* __restrict__ aout) {
  __shared__ u16 kv_lds[2][2][4096];  // [buf][K/V][64x64 tile, swizzled]
  __shared__ __bf16 p_lds[4][16][72];
  const int tid = threadIdx.x;
  const int wid = tid >> 6;
  const int lane = tid & 63;
  const int lr = lane & 15;
  const int lg = lane >> 4;
  const int qt = 31 - blockIdx.x;  // descending: biggest blocks first
  const int bh = blockIdx.y;
  const int b = bh >> 4, h = bh & 15;
  const int qbase = qt * 64;
  const int qr0 = qbase + wid * 16;

  const float LOG2E = 1.4426950408889634f;
  const float c1 = 0.125f * LOG2E;
  const float c2 = exp2f(-(float)(h + 1) * 0.5f) * LOG2E;

  const __bf16* qrow = qb + (size_t)(b * 2048 + qr0 + lr) * 1024 + h * 64;
  bf16x8 qf0 = *(const bf16x8*)(qrow + lg * 8);
  bf16x8 qf1 = *(const bf16x8*)(qrow + 32 + lg * 8);

  bf16x8 ones;
#pragma unroll
  for (int j = 0; j < 8; ++j) ones[j] = (__bf16)1.0f;

  float m[4], l[4], cq[4];
  f32x4 o[4];
#pragma unroll
  for (int r = 0; r < 4; ++r) {
    m[r] = -1e30f;
    l[r] = 0.f;
    cq[r] = c2 * (float)(qr0 + lg * 4 + r);
  }
#pragma unroll
  for (int dt = 0; dt < 4; ++dt) o[dt] = (f32x4){0.f, 0.f, 0.f, 0.f};

  const __bf16* ktiles = kp + (size_t)bh * 32 * 4096;
  const __bf16* vtiles = vp + (size_t)bh * 32 * 4096;

  // stage tile t into buffer bf: waves 0,1 stage K; waves 2,3 stage V
  auto stage = [&](int bf, int t) {
    if (wid < 2) {
      const __bf16* src = ktiles + (size_t)t * 4096;
#pragma unroll
      for (int j = 0; j < 4; ++j) {
        int off = (wid * 4 + j) * 512;
        gll16(src + off + lane * 8, (char*)&kv_lds[bf][0][0] + off * 2);
      }
    } else {
      const __bf16* src = vtiles + (size_t)t * 4096;
#pragma unroll
      for (int j = 0; j < 4; ++j) {
        int off = ((wid - 2) * 4 + j) * 512;
        gll16(src + off + lane * 8, (char*)&kv_lds[bf][1][0] + off * 2);
      }
    }
  };

  stage(0, 0);
  int buf = 0;
  const int ntiles = qt + 1;
  const int sx0 = (lg ^ (lr & 7)) << 3;        // swizzled chunk for frag0
  const int sx1 = ((lg + 4) ^ (lr & 7)) << 3;  // swizzled chunk for frag1

  for (int t = 0; t < ntiles; ++t) {
    __syncthreads();  // staged tile t visible (drains vmcnt)
    if (t + 1 < ntiles) stage(buf ^ 1, t + 1);
    const u16* kbuf = kv_lds[buf][0];
    const u16* vbuf = kv_lds[buf][1];
    const int kv = t * 64;
    const bool diag = (t == qt);

    // ---- QK^T ----
    f32x4 s[4];
#pragma unroll
    for (int nt = 0; nt < 4; ++nt) {
      int rb = (nt * 16 + lr) * 64;
      bf16x8 k0 = *(const bf16x8*)&kbuf[rb + sx0];
      bf16x8 k1 = *(const bf16x8*)&kbuf[rb + sx1];
      f32x4 tt = (f32x4){0.f, 0.f, 0.f, 0.f};
      tt = mfma16(qf0, k0, tt);
      tt = mfma16(qf1, k1, tt);
      s[nt] = tt;
    }

    // ---- logits + online softmax ----
#pragma unroll
    for (int nt = 0; nt < 4; ++nt) {
      float bnt = c2 * (float)(kv + nt * 16 + lr);
#pragma unroll
      for (int r = 0; r < 4; ++r)
        s[nt][r] = __builtin_fmaf(s[nt][r], c1, bnt - cq[r]);
    }
    if (diag) {
#pragma unroll
      for (int nt = 0; nt < 4; ++nt) {
        float kf = (float)(kv + nt * 16 + lr);
#pragma unroll
        for (int r = 0; r < 4; ++r) {
          float qi = (float)(qr0 + lg * 4 + r);
          if (kf > qi) s[nt][r] = -1e30f;
        }
      }
    }
    float rmax[4];
#pragma unroll
    for (int r = 0; r < 4; ++r)
      rmax[r] = fmaxf(fmaxf(s[0][r], s[1][r]), fmaxf(s[2][r], s[3][r]));
#pragma unroll
    for (int r = 0; r < 4; ++r)
#pragma unroll
      for (int d = 1; d < 16; d <<= 1)
        rmax[r] = fmaxf(rmax[r], __shfl_xor(rmax[r], d));
    float fac[4];
#pragma unroll
    for (int r = 0; r < 4; ++r) {
      float mn = fmaxf(m[r], rmax[r]);
      fac[r] = __builtin_amdgcn_exp2f(m[r] - mn);
      m[r] = mn;
      l[r] *= fac[r];
    }
#pragma unroll
    for (int dt = 0; dt < 4; ++dt)
#pragma unroll
      for (int r = 0; r < 4; ++r) o[dt][r] *= fac[r];
#pragma unroll
    for (int nt = 0; nt < 4; ++nt)
#pragma unroll
      for (int r = 0; r < 4; ++r) {
        float e = __builtin_amdgcn_exp2f(s[nt][r] - m[r]);
        p_lds[wid][lg * 4 + r][nt * 16 + lr] = (__bf16)e;
      }

    // wave-private LDS buffer: lgkmcnt ordering, no barrier needed
    bf16x8 pa0 = *(const bf16x8*)&p_lds[wid][lr][lg * 8];
    bf16x8 pa1 = *(const bf16x8*)&p_lds[wid][lr][32 + lg * 8];

    // ---- row-sum via ones-MFMA ----
    {
      f32x4 tt = (f32x4){0.f, 0.f, 0.f, 0.f};
      tt = mfma16(pa0, ones, tt);
      tt = mfma16(pa1, ones, tt);
#pragma unroll
      for (int r = 0; r < 4; ++r) l[r] += tt[r];
    }

    // ---- PV ----
#pragma unroll
    for (int dt = 0; dt < 4; ++dt) {
      int rb = (dt * 16 + lr) * 64;
      bf16x8 v0 = *(const bf16x8*)&vbuf[rb + sx0];
      bf16x8 v1 = *(const bf16x8*)&vbuf[rb + sx1];
      o[dt] = mfma16(pa0, v0, o[dt]);
      o[dt] = mfma16(pa1, v1, o[dt]);
    }
    buf ^= 1;
  }

  // ---- epilogue ----
#pragma unroll
  for (int dt = 0; dt < 4; ++dt)
#pragma unroll
    for (int r = 0; r < 4; ++r) {
      float val = o[dt][r] / l[r];
      aout[(size_t)(b * 2048 + qr0 + lg * 4 + r) * 1024 + h * 64 + dt * 16 + lr] =
          (__bf16)val;
    }
}

extern "C" void kernel_launch(void* const* d_in, const int* in_sizes, int n_in,
                              void* d_out, int out_size, void* d_ws, size_t ws_size,
                              hipStream_t stream) {
  (void)in_sizes; (void)n_in; (void)out_size; (void)ws_size;
  const float* x = (const float*)d_in[0];
  const float* Wp = (const float*)d_in[1];
  const float* bp = (const float*)d_in[2];
  const float* Wo = (const float*)d_in[3];
  const float* bo = (const float*)d_in[4];
  float* out = (float*)d_out;

  char* ws = (char*)d_ws;
  u16* xb  = (u16*)(ws);                        // 8 MB  x bf16 [4096,1024]
  u16* wpb = (u16*)(ws + (size_t)(8u << 20));   // 6 MB  W_packed bf16
  u16* wob = (u16*)(ws + (size_t)(14u << 20));  // 2 MB  W_out bf16
  u16* qbp = (u16*)(ws + (size_t)(16u << 20));  // 8 MB  Q [4096,1024]
  u16* kpp = (u16*)(ws + (size_t)(24u << 20));  // 8 MB  K packed tiles
  u16* vpp = (u16*)(ws + (size_t)(32u << 20));  // 8 MB  V packed tiles
  u16* ab  = xb;  // attention output reuses x_bf16 space

  cvt_kernel<<<2048, 256, 0, stream>>>(x, (__bf16*)xb, 4096 * 1024 / 8);
  cvt_kernel<<<1536, 256, 0, stream>>>(Wp, (__bf16*)wpb, 3072 * 1024 / 8);
  cvt_kernel<<<512, 256, 0, stream>>>(Wo, (__bf16*)wob, 1024 * 1024 / 8);
  gemm_bt<1><<<dim3(32, 24), 256, 0, stream>>>(
      xb, wpb, bp, nullptr, (__bf16*)qbp, (__bf16*)kpp, (__bf16*)vpp,
      4096, 3072, 1024);
  attn_kernel<<<dim3(32, 32), 256, 0, stream>>>(
      (const __bf16*)qbp, (const __bf16*)kpp, (const __bf16*)vpp, (__bf16*)ab);
  gemm_bt<0><<<dim3(32, 8), 256, 0, stream>>>(
      ab, wob, bo, out, nullptr, nullptr, nullptr, 4096, 1024, 1024);
}

// Round 4
// 128.564 us; speedup vs baseline: 2.3866x; 1.3352x over previous
//
#include <hip/hip_runtime.h>

typedef float f32x4 __attribute__((ext_vector_type(4)));
typedef __bf16 bf16x8 __attribute__((ext_vector_type(8)));
typedef unsigned short u16;

__device__ __forceinline__ f32x4 mfma16(bf16x8 a, bf16x8 b, f32x4 c) {
  return __builtin_amdgcn_mfma_f32_16x16x32_bf16(a, b, c, 0, 0, 0);
}

__device__ __forceinline__ void gll16(const void* g, void* l) {
  __builtin_amdgcn_global_load_lds(
      (const __attribute__((address_space(1))) void*)g,
      (__attribute__((address_space(3))) void*)l, 16, 0, 0);
}

// ---------------- f32 -> bf16 convert ----------------
__global__ void cvt_kernel(const float* __restrict__ in, __bf16* __restrict__ out, int n8) {
  int idx = blockIdx.x * blockDim.x + threadIdx.x;
  int stride = gridDim.x * blockDim.x;
  for (int i = idx; i < n8; i += stride) {
    const float* p = in + (size_t)i * 8;
    f32x4 a = *(const f32x4*)p;
    f32x4 b = *(const f32x4*)(p + 4);
    bf16x8 r;
#pragma unroll
    for (int j = 0; j < 4; ++j) {
      r[j] = (__bf16)a[j];
      r[4 + j] = (__bf16)b[j];
    }
    *(bf16x8*)(out + (size_t)i * 8) = r;
  }
}

// ---------------- bf16 GEMM: C = A @ B^T + bias ----------------
// MODE 0: plain f32 output to Cout.
// MODE 1: QKV pack: Q -> qb [4096,1024]; K -> kp tiles [bh][t][s'][d] swizzled;
//         V -> vp tiles [bh][t][d][s'] swizzled. chunk(col16B) ^= (row&7).
template <int MODE>
__global__ __launch_bounds__(256, 2) void gemm_bt(
    const u16* __restrict__ A, const u16* __restrict__ B,
    const float* __restrict__ bias, float* __restrict__ Cout,
    __bf16* __restrict__ qb, __bf16* __restrict__ kp, __bf16* __restrict__ vp,
    int M, int N, int K) {
  __shared__ u16 lA[128 * 32];
  __shared__ u16 lB[128 * 32];
  const int tid = threadIdx.x;
  const int wid = tid >> 6;
  const int lane = tid & 63;
  const int lr = lane & 15;
  const int lg = lane >> 4;
  const int bm = blockIdx.x * 128;
  const int bn = blockIdx.y * 128;
  const int wm = (wid >> 1) * 64;
  const int wn = (wid & 1) * 64;

  f32x4 acc[4][4] = {};

  for (int kt = 0; kt < K; kt += 32) {
    __syncthreads();
#pragma unroll
    for (int j = 0; j < 2; ++j) {
      int beta = tid * 16 + j * 4096;
      int row = beta >> 6;
      int ce = (beta & 63) >> 1;
      gll16(A + (size_t)(bm + row) * K + kt + ce,
            (char*)lA + (wid << 10) + (j << 12));
      gll16(B + (size_t)(bn + row) * K + kt + ce,
            (char*)lB + (wid << 10) + (j << 12));
    }
    __syncthreads();
    bf16x8 af[4], bfr[4];
#pragma unroll
    for (int mt = 0; mt < 4; ++mt)
      af[mt] = *(const bf16x8*)&lA[(wm + mt * 16 + lr) * 32 + lg * 8];
#pragma unroll
    for (int nt = 0; nt < 4; ++nt)
      bfr[nt] = *(const bf16x8*)&lB[(wn + nt * 16 + lr) * 32 + lg * 8];
#pragma unroll
    for (int mt = 0; mt < 4; ++mt)
#pragma unroll
      for (int nt = 0; nt < 4; ++nt)
        acc[mt][nt] = mfma16(af[mt], bfr[nt], acc[mt][nt]);
  }

#pragma unroll
  for (int nt = 0; nt < 4; ++nt) {
    int col = bn + wn + nt * 16 + lr;
    float bv = bias[col];
#pragma unroll
    for (int mt = 0; mt < 4; ++mt) {
#pragma unroll
      for (int r = 0; r < 4; ++r) {
        int row = bm + wm + mt * 16 + lg * 4 + r;
        float val = acc[mt][nt][r] + bv;
        if (MODE == 0) {
          Cout[(size_t)row * N + col] = val;
        } else {
          __bf16 bx = (__bf16)val;
          int b = row >> 11, s = row & 2047;
          int third = col >> 10, hd = col & 1023;
          int h = hd >> 6, d = hd & 63;
          if (third == 0) {
            qb[(size_t)row * 1024 + hd] = bx;
          } else {
            int bh = b * 16 + h, t = s >> 6, sr = s & 63;
            size_t tb = ((size_t)(bh * 32 + t)) * 4096;
            if (third == 1)
              kp[tb + sr * 64 + (((d >> 3) ^ (sr & 7)) << 3) + (d & 7)] = bx;
            else
              vp[tb + d * 64 + ((((sr >> 3)) ^ (d & 7)) << 3) + (sr & 7)] = bx;
          }
        }
      }
    }
  }
}

// ---------------- fused causal+ALiBi flash attention ----------------
// Uniform-work pairing: block handles qtiles (63-pr) then (pr), QBLK=32,
// exactly 33 kv-tiles per block. 2 waves/block, wave = 16 q rows.
// XCD swizzle: 4 bh per XCD (K/V set = 2 MB, L2-fit).
// Defer-max online softmax (THR=8 in log2 units, m init 0).
__global__ __launch_bounds__(128, 4) void attn_kernel(
    const __bf16* __restrict__ qb, const __bf16* __restrict__ kp,
    const __bf16* __restrict__ vp, __bf16* __restrict__ aout) {
  __shared__ u16 kv_lds[2][2][4096];  // [buf][K/V][64x64 tile, swizzled]
  __shared__ __bf16 p_lds[2][16][72];
  const int tid = threadIdx.x;
  const int wid = tid >> 6;  // 0: stages K, 1: stages V
  const int lane = tid & 63;
  const int lr = lane & 15;
  const int lg = lane >> 4;

  const int lid = blockIdx.y * 32 + blockIdx.x;
  const int xcd = lid & 7;
  const int slot = lid >> 3;           // 0..127
  const int bh = xcd * 4 + (slot >> 5);
  const int pr = slot & 31;
  const int b = bh >> 4, h = bh & 15;

  const float LOG2E = 1.4426950408889634f;
  const float c1 = 0.125f * LOG2E;
  const float c2 = exp2f(-(float)(h + 1) * 0.5f) * LOG2E;

  bf16x8 ones;
#pragma unroll
  for (int j = 0; j < 8; ++j) ones[j] = (__bf16)1.0f;

  const __bf16* ktiles = kp + (size_t)bh * 32 * 4096;
  const __bf16* vtiles = vp + (size_t)bh * 32 * 4096;

  auto stage = [&](int bf, int t) {
    const __bf16* src = (wid == 0 ? ktiles : vtiles) + (size_t)t * 4096;
    char* dst = (char*)&kv_lds[bf][wid][0];
#pragma unroll
    for (int j = 0; j < 8; ++j)
      gll16(src + j * 512 + lane * 8, dst + j * 1024);
  };

  const int sx0 = (lg ^ (lr & 7)) << 3;        // swizzled chunk, frag0
  const int sx1 = ((lg + 4) ^ (lr & 7)) << 3;  // swizzled chunk, frag1

  int buf = 0;

  for (int ph = 0; ph < 2; ++ph) {
    const int q32 = ph ? pr : 63 - pr;
    const int qbase = q32 * 32;
    const int ntl = (q32 >> 1) + 1;  // kv tiles needed
    const int qr0 = qbase + wid * 16;

    const __bf16* qrow = qb + (size_t)(b * 2048 + qr0 + lr) * 1024 + h * 64;
    bf16x8 qf0 = *(const bf16x8*)(qrow + lg * 8);
    bf16x8 qf1 = *(const bf16x8*)(qrow + 32 + lg * 8);

    float m[4], l[4], cq[4];
    f32x4 o[4];
#pragma unroll
    for (int r = 0; r < 4; ++r) {
      m[r] = 0.f;  // defer-max: safe start, violations handled below
      l[r] = 0.f;
      cq[r] = c2 * (float)(qr0 + lg * 4 + r);
    }
#pragma unroll
    for (int dt = 0; dt < 4; ++dt) o[dt] = (f32x4){0.f, 0.f, 0.f, 0.f};

    stage(buf, 0);

    for (int t = 0; t < ntl; ++t) {
      __syncthreads();  // stage(t) visible (vmcnt+lgkm drained per wave)
      if (t + 1 < ntl) stage(buf ^ 1, t + 1);
      const u16* kbuf = kv_lds[buf][0];
      const u16* vbuf = kv_lds[buf][1];
      const int kv = t * 64;
      const bool last = (t == ntl - 1);

      // ---- QK^T ----
      f32x4 s[4];
#pragma unroll
      for (int nt = 0; nt < 4; ++nt) {
        int rb = (nt * 16 + lr) * 64;
        bf16x8 k0 = *(const bf16x8*)&kbuf[rb + sx0];
        bf16x8 k1 = *(const bf16x8*)&kbuf[rb + sx1];
        f32x4 tt = (f32x4){0.f, 0.f, 0.f, 0.f};
        tt = mfma16(qf0, k0, tt);
        tt = mfma16(qf1, k1, tt);
        s[nt] = tt;
      }

      // ---- logits (log2 domain) ----
#pragma unroll
      for (int nt = 0; nt < 4; ++nt) {
        float bnt = c2 * (float)(kv + nt * 16 + lr);
#pragma unroll
        for (int r = 0; r < 4; ++r)
          s[nt][r] = __builtin_fmaf(s[nt][r], c1, bnt - cq[r]);
      }
      if (last) {  // diagonal tile: causal mask
#pragma unroll
        for (int nt = 0; nt < 4; ++nt) {
          float kf = (float)(kv + nt * 16 + lr);
#pragma unroll
          for (int r = 0; r < 4; ++r) {
            float qi = (float)(qr0 + lg * 4 + r);
            if (kf > qi) s[nt][r] = -1e30f;
          }
        }
      }

      // ---- defer-max check (no cross-lane in common path) ----
      float pm[4];
#pragma unroll
      for (int r = 0; r < 4; ++r)
        pm[r] = fmaxf(fmaxf(s[0][r], s[1][r]), fmaxf(s[2][r], s[3][r]));
      bool ok = (pm[0] <= m[0] + 8.f) && (pm[1] <= m[1] + 8.f) &&
                (pm[2] <= m[2] + 8.f) && (pm[3] <= m[3] + 8.f);
      if (!__all(ok)) {  // rare: full reduce + rescale
#pragma unroll
        for (int r = 0; r < 4; ++r)
#pragma unroll
          for (int d = 1; d < 16; d <<= 1)
            pm[r] = fmaxf(pm[r], __shfl_xor(pm[r], d));
#pragma unroll
        for (int r = 0; r < 4; ++r) {
          float mn = fmaxf(m[r], pm[r]);
          float fac = __builtin_amdgcn_exp2f(m[r] - mn);
          m[r] = mn;
          l[r] *= fac;
#pragma unroll
          for (int dt = 0; dt < 4; ++dt) o[dt][r] *= fac;
        }
      }

      // ---- P = exp2(s - m), store to per-wave LDS ----
#pragma unroll
      for (int nt = 0; nt < 4; ++nt)
#pragma unroll
        for (int r = 0; r < 4; ++r) {
          float e = __builtin_amdgcn_exp2f(s[nt][r] - m[r]);
          p_lds[wid][lg * 4 + r][nt * 16 + lr] = (__bf16)e;
        }

      // wave-private LDS: compiler orders via lgkmcnt, no barrier needed
      bf16x8 pa0 = *(const bf16x8*)&p_lds[wid][lr][lg * 8];
      bf16x8 pa1 = *(const bf16x8*)&p_lds[wid][lr][32 + lg * 8];

      // ---- row-sum via ones-MFMA ----
      {
        f32x4 tt = (f32x4){0.f, 0.f, 0.f, 0.f};
        tt = mfma16(pa0, ones, tt);
        tt = mfma16(pa1, ones, tt);
#pragma unroll
        for (int r = 0; r < 4; ++r) l[r] += tt[r];
      }

      // ---- PV ----
#pragma unroll
      for (int dt = 0; dt < 4; ++dt) {
        int rb = (dt * 16 + lr) * 64;
        bf16x8 v0 = *(const bf16x8*)&vbuf[rb + sx0];
        bf16x8 v1 = *(const bf16x8*)&vbuf[rb + sx1];
        o[dt] = mfma16(pa0, v0, o[dt]);
        o[dt] = mfma16(pa1, v1, o[dt]);
      }
      buf ^= 1;
    }

    // ---- epilogue for this qtile ----
#pragma unroll
    for (int dt = 0; dt < 4; ++dt)
#pragma unroll
      for (int r = 0; r < 4; ++r) {
        float val = o[dt][r] / l[r];
        aout[(size_t)(b * 2048 + qr0 + lg * 4 + r) * 1024 + h * 64 + dt * 16 + lr] =
            (__bf16)val;
      }
  }
}

extern "C" void kernel_launch(void* const* d_in, const int* in_sizes, int n_in,
                              void* d_out, int out_size, void* d_ws, size_t ws_size,
                              hipStream_t stream) {
  (void)in_sizes; (void)n_in; (void)out_size; (void)ws_size;
  const float* x = (const float*)d_in[0];
  const float* Wp = (const float*)d_in[1];
  const float* bp = (const float*)d_in[2];
  const float* Wo = (const float*)d_in[3];
  const float* bo = (const float*)d_in[4];
  float* out = (float*)d_out;

  char* ws = (char*)d_ws;
  u16* xb  = (u16*)(ws);                        // 8 MB  x bf16 [4096,1024]
  u16* wpb = (u16*)(ws + (size_t)(8u << 20));   // 6 MB  W_packed bf16
  u16* wob = (u16*)(ws + (size_t)(14u << 20));  // 2 MB  W_out bf16
  u16* qbp = (u16*)(ws + (size_t)(16u << 20));  // 8 MB  Q [4096,1024]
  u16* kpp = (u16*)(ws + (size_t)(24u << 20));  // 8 MB  K packed tiles
  u16* vpp = (u16*)(ws + (size_t)(32u << 20));  // 8 MB  V packed tiles
  u16* ab  = xb;  // attention output reuses x_bf16 space

  cvt_kernel<<<2048, 256, 0, stream>>>(x, (__bf16*)xb, 4096 * 1024 / 8);
  cvt_kernel<<<1536, 256, 0, stream>>>(Wp, (__bf16*)wpb, 3072 * 1024 / 8);
  cvt_kernel<<<512, 256, 0, stream>>>(Wo, (__bf16*)wob, 1024 * 1024 / 8);
  gemm_bt<1><<<dim3(32, 24), 256, 0, stream>>>(
      xb, wpb, bp, nullptr, (__bf16*)qbp, (__bf16*)kpp, (__bf16*)vpp,
      4096, 3072, 1024);
  attn_kernel<<<dim3(32, 32), 128, 0, stream>>>(
      (const __bf16*)qbp, (const __bf16*)kpp, (const __bf16*)vpp, (__bf16*)ab);
  gemm_bt<0><<<dim3(32, 8), 256, 0, stream>>>(
      ab, wob, bo, out, nullptr, nullptr, nullptr, 4096, 1024, 1024);
}